// Round 4
// baseline (978.894 us; speedup 1.0000x reference)
//
#include <hip/hip_runtime.h>
#include <hip/hip_bf16.h>
#include <math.h>

typedef unsigned short ushort_t;
typedef __bf16 bf16x8 __attribute__((ext_vector_type(8)));
typedef float f32x4 __attribute__((ext_vector_type(4)));

// Problem constants
constexpr int Bb = 8, Ss = 128, Dd = 512, Vv = 32768, Hh = 8, Pp = 2048, Ll = 4, STEPS = 3;
constexpr int Tt = Bb * Ss;          // 1024 tokens
constexpr int DK = Dd / Hh;          // 64
constexpr float SCALE = 0.125f;      // 1/sqrt(64)

// fp32 -> bf16 RNE
__device__ __forceinline__ ushort_t f2b(float f) {
    unsigned u = __float_as_uint(f);
    unsigned r = (u + 0x7FFFu + ((u >> 16) & 1u)) >> 16;
    return (ushort_t)r;
}

__device__ __forceinline__ void gload_lds16(const void* g, void* l) {
    __builtin_amdgcn_global_load_lds((const __attribute__((address_space(1))) void*)g,
                                     (__attribute__((address_space(3))) void*)l, 16, 0, 0);
}

// ---------------------------------------------------------------------------
// One fused f32->bf16 conversion pass over all 7 weight groups.
// Segment k covers f4 indices [end4[k-1], end4[k]); b[k] != nullptr means dst = a+b.
struct CvtSegs {
    const float* a[7];
    const float* b[7];
    ushort_t*    d[7];
    long         end4[7];
};

__global__ __launch_bounds__(256) void cvt_all_k(CvtSegs s) {
    long i = (long)blockIdx.x * 256 + threadIdx.x;   // float4 index
    int k = 0;
    while (k < 6 && i >= s.end4[k]) ++k;
    long base = k ? s.end4[k - 1] : 0;
    long j = i - base;
    float4 v = reinterpret_cast<const float4*>(s.a[k])[j];
    if (s.b[k]) {
        float4 vb = reinterpret_cast<const float4*>(s.b[k])[j];
        v.x += vb.x; v.y += vb.y; v.z += vb.z; v.w += vb.w;
    }
    ushort4 o;
    o.x = f2b(v.x); o.y = f2b(v.y); o.z = f2b(v.z); o.w = f2b(v.w);
    reinterpret_cast<ushort4*>(s.d[k])[j] = o;
}

// ---------------------------------------------------------------------------
// Embedding gather: X[t][d] = emb[tokens[t]][d] (f32 + bf16)
__global__ __launch_bounds__(128) void embed_k(const int* __restrict__ tokens,
                                               const float* __restrict__ emb,
                                               float* __restrict__ X,
                                               ushort_t* __restrict__ Xb) {
    int t = blockIdx.x;
    int tok = tokens[t];
    float4 v = reinterpret_cast<const float4*>(emb + (long)tok * Dd)[threadIdx.x];
    reinterpret_cast<float4*>(X + (long)t * Dd)[threadIdx.x] = v;
    ushort4 o;
    o.x = f2b(v.x); o.y = f2b(v.y); o.z = f2b(v.z); o.w = f2b(v.w);
    reinterpret_cast<ushort4*>(Xb + (long)t * Dd)[threadIdx.x] = o;
}

// ---------------------------------------------------------------------------
// bf16 MFMA GEMM: C[M,N] = A[M,K] @ W[N,K]^T + b1[N] (+b2[N]) (+ReLU)
// A, W bf16 row-major (K contiguous). 256 thr = 4 waves (2x2), tile BMxBN.
// LDS staged via global_load_lds (linear dest) with both-sides XOR swizzle.
template <int BM, int BN, int BK, int RELU, int BOUT>
__global__ __launch_bounds__(256) void gemm_bf16(const ushort_t* __restrict__ A,
                                                 const ushort_t* __restrict__ W,
                                                 const float* __restrict__ b1,
                                                 const float* __restrict__ b2,
                                                 float* __restrict__ C,
                                                 ushort_t* __restrict__ Cb,
                                                 int M, int N, int K) {
    constexpr int CH = BK / 8;                 // 16B chunks per row
    constexpr int SH = (CH == 4) ? 1 : 0;      // swizzle row shift (bank period)
    constexpr int WM = BM / 2, WN = BN / 2;    // wave sub-tile
    constexpr int FM = WM / 16, FN = WN / 16;  // 16x16 fragments per wave
    constexpr int LA = BM * BK / 2048;         // 16B loads per thread per tile
    constexpr int LW = BN * BK / 2048;

    __shared__ __align__(16) ushort_t As[BM * BK];
    __shared__ __align__(16) ushort_t Ws[BN * BK];

    const int tid = threadIdx.x;
    const int lane = tid & 63, wid = tid >> 6;
    const int wr = wid >> 1, wc = wid & 1;
    const int row0 = blockIdx.y * BM, col0 = blockIdx.x * BN;

    f32x4 acc[FM][FN];
#pragma unroll
    for (int m = 0; m < FM; ++m)
#pragma unroll
        for (int n = 0; n < FN; ++n) acc[m][n] = (f32x4)(0.0f);

    for (int k0 = 0; k0 < K; k0 += BK) {
        // stage A tile: LDS linear; global source pre-swizzled (rule #21)
#pragma unroll
        for (int i = 0; i < LA; ++i) {
            int j = i * 256 + tid;                 // chunk id in tile
            int prow = j >> (CH == 4 ? 2 : 3);
            int pkg = j & (CH - 1);
            int skg = pkg ^ ((prow >> SH) & (CH - 1));
            gload_lds16(A + (long)(row0 + prow) * K + k0 + skg * 8,
                        &As[(i * 256 + wid * 64) * 8]);
        }
#pragma unroll
        for (int i = 0; i < LW; ++i) {
            int j = i * 256 + tid;
            int prow = j >> (CH == 4 ? 2 : 3);
            int pkg = j & (CH - 1);
            int skg = pkg ^ ((prow >> SH) & (CH - 1));
            gload_lds16(W + (long)(col0 + prow) * K + k0 + skg * 8,
                        &Ws[(i * 256 + wid * 64) * 8]);
        }
        __syncthreads();

#pragma unroll
        for (int kk = 0; kk < BK / 32; ++kk) {
            bf16x8 af[FM], wf[FN];
#pragma unroll
            for (int m = 0; m < FM; ++m) {
                int r = wr * WM + m * 16 + (lane & 15);
                int cl = kk * 4 + (lane >> 4);
                int cs = cl ^ ((r >> SH) & (CH - 1));
                af[m] = *reinterpret_cast<const bf16x8*>(&As[r * BK + cs * 8]);
            }
#pragma unroll
            for (int n = 0; n < FN; ++n) {
                int r = wc * WN + n * 16 + (lane & 15);
                int cl = kk * 4 + (lane >> 4);
                int cs = cl ^ ((r >> SH) & (CH - 1));
                wf[n] = *reinterpret_cast<const bf16x8*>(&Ws[r * BK + cs * 8]);
            }
#pragma unroll
            for (int m = 0; m < FM; ++m)
#pragma unroll
                for (int n = 0; n < FN; ++n)
                    acc[m][n] = __builtin_amdgcn_mfma_f32_16x16x32_bf16(
                        af[m], wf[n], acc[m][n], 0, 0, 0);
        }
        __syncthreads();
    }

    // epilogue: C/D layout col=lane&15, row=(lane>>4)*4+j (m89-verified)
#pragma unroll
    for (int n = 0; n < FN; ++n) {
        int col = col0 + wc * WN + n * 16 + (lane & 15);
        float bias = b1[col];
        if (b2) bias += b2[col];
#pragma unroll
        for (int m = 0; m < FM; ++m) {
#pragma unroll
            for (int j = 0; j < 4; ++j) {
                int row = row0 + wr * WM + m * 16 + (lane >> 4) * 4 + j;
                float v = acc[m][n][j] + bias;
                if (RELU) v = fmaxf(v, 0.f);
                if (BOUT) Cb[(long)row * N + col] = f2b(v);
                else      C[(long)row * N + col] = v;
            }
        }
    }
}

// ---------------------------------------------------------------------------
// Attention: one wave per (b,h,query-row). qkv rows are 3D wide: [q | k | v].
__global__ __launch_bounds__(64) void attn_k(const float* __restrict__ qkv,
                                             ushort_t* __restrict__ Ob) {
    const int id = blockIdx.x;             // b*H*S + h*S + r
    const int r = id % Ss;
    const int bh = id / Ss;
    const int h = bh % Hh;
    const int b = bh / Hh;
    const int lane = threadIdx.x;

    const long rowpitch = 3 * Dd;
    const float* qrow = qkv + (long)(b * Ss + r) * rowpitch + h * DK;
    const int c0 = lane, c1 = lane + 64;
    const float* k0p = qkv + (long)(b * Ss + c0) * rowpitch + Dd + h * DK;
    const float* k1p = qkv + (long)(b * Ss + c1) * rowpitch + Dd + h * DK;

    float s0 = 0.f, s1 = 0.f;
    for (int d = 0; d < DK; ++d) {
        float qd = qrow[d];
        s0 += qd * k0p[d];
        s1 += qd * k1p[d];
    }
    s0 *= SCALE; s1 *= SCALE;
    if (c0 > r) s0 = -INFINITY;
    if (c1 > r) s1 = -INFINITY;

    float mx = fmaxf(s0, s1);
    for (int off = 1; off < 64; off <<= 1) mx = fmaxf(mx, __shfl_xor(mx, off));
    float e0 = (c0 <= r) ? expf(s0 - mx) : 0.f;
    float e1 = (c1 <= r) ? expf(s1 - mx) : 0.f;
    float sum = e0 + e1;
    for (int off = 1; off < 64; off <<= 1) sum += __shfl_xor(sum, off);
    float inv = 1.f / sum;

    __shared__ float p[Ss];
    p[c0] = e0 * inv;
    p[c1] = e1 * inv;
    __syncthreads();

    const float* vbase = qkv + (long)(b * Ss) * rowpitch + 2 * Dd + h * DK + lane;
    float o = 0.f;
    for (int c = 0; c <= r; ++c) o += p[c] * vbase[(long)c * rowpitch];
    Ob[(long)(b * Ss + r) * Dd + h * DK + lane] = f2b(o);
}

// ---------------------------------------------------------------------------
// out = LayerNorm(a + bsrc) * w + bias  -> f32 + bf16
__global__ __launch_bounds__(256) void add_ln_k(float* __restrict__ out,
                                                ushort_t* __restrict__ outb,
                                                const float* __restrict__ a,
                                                const float* __restrict__ bsrc,
                                                const float* __restrict__ w,
                                                const float* __restrict__ bias) {
    const int t = blockIdx.x;
    const int tid = threadIdx.x;
    float2 av = *reinterpret_cast<const float2*>(&a[(long)t * Dd + tid * 2]);
    float2 bv = *reinterpret_cast<const float2*>(&bsrc[(long)t * Dd + tid * 2]);
    float x0 = av.x + bv.x, x1 = av.y + bv.y;
    float s = x0 + x1, ss = x0 * x0 + x1 * x1;
    for (int off = 1; off < 64; off <<= 1) {
        s += __shfl_xor(s, off);
        ss += __shfl_xor(ss, off);
    }
    __shared__ float sm[4], ssm[4];
    int wid = tid >> 6;
    if ((tid & 63) == 0) { sm[wid] = s; ssm[wid] = ss; }
    __syncthreads();
    s = sm[0] + sm[1] + sm[2] + sm[3];
    ss = ssm[0] + ssm[1] + ssm[2] + ssm[3];
    float mean = s * (1.f / Dd);
    float var = ss * (1.f / Dd) - mean * mean;
    float rstd = rsqrtf(var + 1e-5f);
    float o0 = (x0 - mean) * rstd * w[tid * 2] + bias[tid * 2];
    float o1 = (x1 - mean) * rstd * w[tid * 2 + 1] + bias[tid * 2 + 1];
    out[(long)t * Dd + tid * 2]     = o0;
    out[(long)t * Dd + tid * 2 + 1] = o1;
    ushort2 ob; ob.x = f2b(o0); ob.y = f2b(o1);
    *reinterpret_cast<ushort2*>(&outb[(long)t * Dd + tid * 2]) = ob;
}

// ---------------------------------------------------------------------------
// LSTM elementwise: gates rows 4D wide [i|f|g|o].
// Non-last steps: write c and h(bf16, feeds next GEMM).
// Last step: write LAT = addsrc + h (f32+bf16); skip c/h (dead).
__global__ __launch_bounds__(256) void lstm_ew_k(const float* __restrict__ gates,
                                                 ushort_t* __restrict__ hb,
                                                 float* __restrict__ c,
                                                 const float* __restrict__ addsrc,
                                                 float* __restrict__ lat,
                                                 ushort_t* __restrict__ latb,
                                                 int first, int last) {
    int idx = blockIdx.x * 256 + threadIdx.x;   // over T*D
    int t = idx >> 9;
    int d = idx & 511;
    const float* g = gates + (long)t * (4 * Dd);
    float ig = g[d], fg = g[Dd + d], gg = g[2 * Dd + d], og = g[3 * Dd + d];
    float si = 1.f / (1.f + expf(-ig));
    float sf = 1.f / (1.f + expf(-fg));
    float so = 1.f / (1.f + expf(-og));
    float cold = first ? 0.f : c[idx];
    float cn = sf * cold + si * tanhf(gg);
    float hn = so * tanhf(cn);
    if (last) {
        float o = addsrc[idx] + hn;
        lat[idx] = o;
        latb[idx] = f2b(o);
    } else {
        c[idx] = cn;
        hb[idx] = f2b(hn);
    }
}

// ---------------------------------------------------------------------------
extern "C" void kernel_launch(void* const* d_in, const int* in_sizes, int n_in,
                              void* d_out, int out_size, void* d_ws, size_t ws_size,
                              hipStream_t stream) {
    const int*   tokens     = (const int*)  d_in[0];
    const float* emb        = (const float*)d_in[1];
    const float* in_proj_w  = (const float*)d_in[2];
    const float* in_proj_b  = (const float*)d_in[3];
    const float* attn_out_w = (const float*)d_in[4];
    const float* attn_out_b = (const float*)d_in[5];
    const float* ln1_w      = (const float*)d_in[6];
    const float* ln1_b      = (const float*)d_in[7];
    const float* lstm_wih   = (const float*)d_in[8];
    const float* lstm_whh   = (const float*)d_in[9];
    const float* lstm_bih   = (const float*)d_in[10];
    const float* lstm_bhh   = (const float*)d_in[11];
    const float* ff_w1      = (const float*)d_in[12];
    const float* ff_b1      = (const float*)d_in[13];
    const float* ff_w2      = (const float*)d_in[14];
    const float* ff_b2      = (const float*)d_in[15];
    const float* ln2_w      = (const float*)d_in[16];
    const float* ln2_b      = (const float*)d_in[17];
    const float* head_w     = (const float*)d_in[18];
    const float* head_bias  = (const float*)d_in[19];
    float* out = (float*)d_out;

    // ---- workspace layout ----
    const long TD = (long)Tt * Dd;          // 524288
    float* ws   = (float*)d_ws;
    float* X    = ws;
    float* Cst  = X + TD;                   // LSTM cell state
    float* LAT  = Cst + TD;
    float* Ta   = LAT + TD;                 // ffn2 out
    float* Tb   = Ta + TD;                  // out-proj out
    float* BIG  = Tb + TD;                  // 1024 x 2048 (qkv / gates / ffn1)
    ushort_t* Xb    = (ushort_t*)(BIG + (long)Tt * 2048);
    ushort_t* Hbb   = Xb + TD;
    ushort_t* LATb  = Hbb + TD;
    ushort_t* Tab   = LATb + TD;
    ushort_t* BIGb  = Tab + TD;             // 1024 x 2048
    ushort_t* ipw   = BIGb + (long)Tt * 2048;   // 4 x 1536 x 512
    ushort_t* aow   = ipw + (long)Ll * 3 * Dd * Dd;
    ushort_t* wihb  = aow + (long)Ll * Dd * Dd;
    ushort_t* wsumb = wihb + (long)Ll * 4 * Dd * Dd;
    ushort_t* ff1b  = wsumb + (long)Ll * 4 * Dd * Dd;
    ushort_t* ff2b  = ff1b + (long)Ll * Pp * Dd;
    ushort_t* hwb   = ff2b + (long)Ll * Dd * Pp;

    // ---- one fused weight conversion pass ----
    CvtSegs segs;
    const long n4_ipw  = (long)Ll * 3 * Dd * Dd / 4;
    const long n4_aow  = (long)Ll * Dd * Dd / 4;
    const long n4_lstm = (long)Ll * 4 * Dd * Dd / 4;
    const long n4_ff   = (long)Ll * Pp * Dd / 4;
    const long n4_head = (long)Vv * Dd / 4;
    long cum = 0;
    auto set = [&](int k, const float* a, const float* b, ushort_t* d, long n4) {
        segs.a[k] = a; segs.b[k] = b; segs.d[k] = d; cum += n4; segs.end4[k] = cum;
    };
    set(0, in_proj_w,  nullptr,  ipw,   n4_ipw);
    set(1, attn_out_w, nullptr,  aow,   n4_aow);
    set(2, lstm_wih,   nullptr,  wihb,  n4_lstm);
    set(3, lstm_wih,   lstm_whh, wsumb, n4_lstm);
    set(4, ff_w1,      nullptr,  ff1b,  n4_ff);
    set(5, ff_w2,      nullptr,  ff2b,  n4_ff);
    set(6, head_w,     nullptr,  hwb,   n4_head);
    cvt_all_k<<<(int)(cum / 256), 256, 0, stream>>>(segs);

    embed_k<<<Tt, 128, 0, stream>>>(tokens, emb, X, Xb);

    for (int l = 0; l < Ll; ++l) {
        // --- attention ---
        gemm_bf16<64, 64, 64, 0, 0><<<dim3(3 * Dd / 64, Tt / 64), 256, 0, stream>>>(
            Xb, ipw + (long)l * 3 * Dd * Dd, in_proj_b + (long)l * 3 * Dd, nullptr,
            BIG, nullptr, Tt, 3 * Dd, Dd);
        attn_k<<<Bb * Hh * Ss, 64, 0, stream>>>(BIG, Tab);
        gemm_bf16<64, 64, 64, 0, 0><<<dim3(Dd / 64, Tt / 64), 256, 0, stream>>>(
            Tab, aow + (long)l * Dd * Dd, attn_out_b + (long)l * Dd, nullptr,
            Tb, nullptr, Tt, Dd, Dd);
        add_ln_k<<<Tt, 256, 0, stream>>>(X, Xb, X, Tb,
                                         ln1_w + (long)l * Dd, ln1_b + (long)l * Dd);

        // --- LSTM latent recurrence (latent==h after step 1 -> wsum folding) ---
        const float* bih = lstm_bih + (long)l * 4 * Dd;
        const float* bhh = lstm_bhh + (long)l * 4 * Dd;
        gemm_bf16<64, 128, 64, 0, 0><<<dim3(4 * Dd / 128, Tt / 64), 256, 0, stream>>>(
            Xb, wihb + (long)l * 4 * Dd * Dd, bih, bhh, BIG, nullptr, Tt, 4 * Dd, Dd);
        lstm_ew_k<<<(Tt * Dd) / 256, 256, 0, stream>>>(BIG, Hbb, Cst,
                                                       nullptr, nullptr, nullptr, 1, 0);
        gemm_bf16<64, 128, 64, 0, 0><<<dim3(4 * Dd / 128, Tt / 64), 256, 0, stream>>>(
            Hbb, wsumb + (long)l * 4 * Dd * Dd, bih, bhh, BIG, nullptr, Tt, 4 * Dd, Dd);
        lstm_ew_k<<<(Tt * Dd) / 256, 256, 0, stream>>>(BIG, Hbb, Cst,
                                                       nullptr, nullptr, nullptr, 0, 0);
        gemm_bf16<64, 128, 64, 0, 0><<<dim3(4 * Dd / 128, Tt / 64), 256, 0, stream>>>(
            Hbb, wsumb + (long)l * 4 * Dd * Dd, bih, bhh, BIG, nullptr, Tt, 4 * Dd, Dd);
        lstm_ew_k<<<(Tt * Dd) / 256, 256, 0, stream>>>(BIG, Hbb, Cst,
                                                       X, LAT, LATb, 0, 1);

        // --- feed forward ---
        gemm_bf16<64, 128, 64, 1, 1><<<dim3(Pp / 128, Tt / 64), 256, 0, stream>>>(
            LATb, ff1b + (long)l * Pp * Dd, ff_b1 + (long)l * Pp, nullptr,
            nullptr, BIGb, Tt, Pp, Dd);
        gemm_bf16<64, 64, 64, 0, 0><<<dim3(Dd / 64, Tt / 64), 256, 0, stream>>>(
            BIGb, ff2b + (long)l * Dd * Pp, ff_b2 + (long)l * Dd, nullptr,
            Ta, nullptr, Tt, Dd, Pp);
        add_ln_k<<<Tt, 256, 0, stream>>>(X, Xb, LAT, Ta,
                                         ln2_w + (long)l * Dd, ln2_b + (long)l * Dd);
    }

    // --- head: M=1024, N=32768, K=512 -> 128x128 tile, 2048 blocks ---
    gemm_bf16<128, 128, 32, 0, 0><<<dim3(Vv / 128, Tt / 128), 256, 0, stream>>>(
        Xb, hwb, head_bias, nullptr, out, nullptr, Tt, Vv, Dd);
}

// Round 5
// 743.848 us; speedup vs baseline: 1.3160x; 1.3160x over previous
//
#include <hip/hip_runtime.h>
#include <hip/hip_bf16.h>
#include <math.h>

typedef unsigned short ushort_t;
typedef __bf16 bf16x8 __attribute__((ext_vector_type(8)));
typedef float f32x4 __attribute__((ext_vector_type(4)));

// Problem constants
constexpr int Bb = 8, Ss = 128, Dd = 512, Vv = 32768, Hh = 8, Pp = 2048, Ll = 4;
constexpr int Tt = Bb * Ss;          // 1024 tokens
constexpr int DK = Dd / Hh;          // 64
constexpr float SCALE = 0.125f;      // 1/sqrt(64)

// fp32 -> bf16 RNE
__device__ __forceinline__ ushort_t f2b(float f) {
    unsigned u = __float_as_uint(f);
    unsigned r = (u + 0x7FFFu + ((u >> 16) & 1u)) >> 16;
    return (ushort_t)r;
}

__device__ __forceinline__ void gload_lds16(const void* g, void* l) {
    __builtin_amdgcn_global_load_lds((const __attribute__((address_space(1))) void*)g,
                                     (__attribute__((address_space(3))) void*)l, 16, 0, 0);
}

// ---------------------------------------------------------------------------
// Fused conversion pass. mode: 0=copy,1=a+b,2=perm-LSTM-W copy,3=perm-LSTM-W a+b,
// 4=perm-LSTM-bias a+b (f32 out). Gate interleave: reordered row r' <- src row
// g*512+d with g=(r'>>4)&3, d=(r'>>6)*16+(r'&15)  (matches LSTM GEMM epilogue).
struct CvtSegs {
    const float* a[8];
    const float* b[8];
    void*        d[8];
    long         end4[8];
    int          mode[8];
};

__global__ __launch_bounds__(256) void cvt_all_k(CvtSegs s) {
    long i = (long)blockIdx.x * 256 + threadIdx.x;   // float4 index
    int k = 0;
    while (k < 7 && i >= s.end4[k]) ++k;
    long base = k ? s.end4[k - 1] : 0;
    long j = i - base;
    int mode = s.mode[k];
    long srcj = j;
    if (mode == 2 || mode == 3) {
        const long per = 2048L * 128;          // f4 per layer
        long layer = j / per, rem = j % per;
        long drow = rem >> 7, col4 = rem & 127;
        long g = (drow >> 4) & 3, d = (drow >> 6) * 16 + (drow & 15);
        srcj = layer * per + (g * 512 + d) * 128 + col4;
    } else if (mode == 4) {
        const long per = 512;                  // f4 per layer (2048 elems)
        long layer = j / per, rem = j % per;
        long e0 = rem * 4;
        long g = (e0 >> 4) & 3, d = (e0 >> 6) * 16 + (e0 & 15);
        srcj = layer * per + (g * 512 + d) / 4;
    }
    float4 v = reinterpret_cast<const float4*>(s.a[k])[srcj];
    if (s.b[k]) {
        float4 vb = reinterpret_cast<const float4*>(s.b[k])[srcj];
        v.x += vb.x; v.y += vb.y; v.z += vb.z; v.w += vb.w;
    }
    if (mode == 4) {
        reinterpret_cast<float4*>(s.d[k])[j] = v;
    } else {
        ushort4 o;
        o.x = f2b(v.x); o.y = f2b(v.y); o.z = f2b(v.z); o.w = f2b(v.w);
        reinterpret_cast<ushort4*>(s.d[k])[j] = o;
    }
}

// ---------------------------------------------------------------------------
__global__ __launch_bounds__(128) void embed_k(const int* __restrict__ tokens,
                                               const float* __restrict__ emb,
                                               float* __restrict__ X,
                                               ushort_t* __restrict__ Xb) {
    int t = blockIdx.x;
    int tok = tokens[t];
    float4 v = reinterpret_cast<const float4*>(emb + (long)tok * Dd)[threadIdx.x];
    reinterpret_cast<float4*>(X + (long)t * Dd)[threadIdx.x] = v;
    ushort4 o;
    o.x = f2b(v.x); o.y = f2b(v.y); o.z = f2b(v.z); o.w = f2b(v.w);
    reinterpret_cast<ushort4*>(Xb + (long)t * Dd)[threadIdx.x] = o;
}

// ---------------------------------------------------------------------------
// bf16 MFMA GEMM, 2-phase double-buffered (stage t+1 before compute t; one
// barrier per K-iter — syncthreads' vmcnt(0)+lgkmcnt(0) drain covers both).
// EPI: 0 = f32 out (+bias); 1 = bf16 out (+bias); 2 = ReLU bf16 out (+bias);
//      3/4/5 = fused LSTM cell (first/mid/last) on gate-interleaved layout.
template <int BM, int BN, int BK, int EPI>
__global__ __launch_bounds__(256) void gemm_bf16(const ushort_t* __restrict__ A,
                                                 const ushort_t* __restrict__ W,
                                                 const float* __restrict__ b1,
                                                 float* __restrict__ C,
                                                 ushort_t* __restrict__ Cb,
                                                 float* __restrict__ cst,
                                                 const float* __restrict__ addsrc,
                                                 float* __restrict__ lat,
                                                 ushort_t* __restrict__ latb,
                                                 int M, int N, int K) {
    constexpr int CH = BK / 8;                 // 16B chunks per row
    constexpr int SH = (CH == 4) ? 1 : 0;      // swizzle shift
    constexpr int WM = BM / 2, WN = BN / 2;
    constexpr int FM = WM / 16, FN = WN / 16;
    constexpr int LA = BM * BK / 2048;
    constexpr int LW = BN * BK / 2048;

    __shared__ __align__(16) ushort_t As[2][BM * BK];
    __shared__ __align__(16) ushort_t Ws[2][BN * BK];

    const int tid = threadIdx.x;
    const int lane = tid & 63, wid = tid >> 6;
    const int wr = wid >> 1, wc = wid & 1;
    const int row0 = blockIdx.y * BM, col0 = blockIdx.x * BN;

    auto stage = [&](int buf, int k0) {
#pragma unroll
        for (int i = 0; i < LA; ++i) {
            int j = i * 256 + tid;
            int prow = j / CH;
            int pkg = j & (CH - 1);
            int skg = pkg ^ ((prow >> SH) & (CH - 1));
            gload_lds16(A + (long)(row0 + prow) * K + k0 + skg * 8,
                        &As[buf][(i * 256 + wid * 64) * 8]);
        }
#pragma unroll
        for (int i = 0; i < LW; ++i) {
            int j = i * 256 + tid;
            int prow = j / CH;
            int pkg = j & (CH - 1);
            int skg = pkg ^ ((prow >> SH) & (CH - 1));
            gload_lds16(W + (long)(col0 + prow) * K + k0 + skg * 8,
                        &Ws[buf][(i * 256 + wid * 64) * 8]);
        }
    };

    f32x4 acc[FM][FN];
#pragma unroll
    for (int m = 0; m < FM; ++m)
#pragma unroll
        for (int n = 0; n < FN; ++n) acc[m][n] = (f32x4)(0.0f);

    const int NT = K / BK;
    stage(0, 0);
    __syncthreads();
    for (int t = 0; t < NT; ++t) {
        int cur = t & 1;
        if (t + 1 < NT) stage(cur ^ 1, (t + 1) * BK);
        const ushort_t* Ab = As[cur];
        const ushort_t* Wb = Ws[cur];
#pragma unroll
        for (int kk = 0; kk < BK / 32; ++kk) {
            bf16x8 af[FM], wf[FN];
#pragma unroll
            for (int m = 0; m < FM; ++m) {
                int r = wr * WM + m * 16 + (lane & 15);
                int cl = kk * 4 + (lane >> 4);
                int cs = cl ^ ((r >> SH) & (CH - 1));
                af[m] = *reinterpret_cast<const bf16x8*>(&Ab[r * BK + cs * 8]);
            }
#pragma unroll
            for (int n = 0; n < FN; ++n) {
                int r = wc * WN + n * 16 + (lane & 15);
                int cl = kk * 4 + (lane >> 4);
                int cs = cl ^ ((r >> SH) & (CH - 1));
                wf[n] = *reinterpret_cast<const bf16x8*>(&Wb[r * BK + cs * 8]);
            }
#pragma unroll
            for (int m = 0; m < FM; ++m)
#pragma unroll
                for (int n = 0; n < FN; ++n)
                    acc[m][n] = __builtin_amdgcn_mfma_f32_16x16x32_bf16(
                        af[m], wf[n], acc[m][n], 0, 0, 0);
        }
        __syncthreads();
    }

    if constexpr (EPI <= 2) {
#pragma unroll
        for (int n = 0; n < FN; ++n) {
            int col = col0 + wc * WN + n * 16 + (lane & 15);
            float bias = b1[col];
#pragma unroll
            for (int m = 0; m < FM; ++m) {
#pragma unroll
                for (int j = 0; j < 4; ++j) {
                    int row = row0 + wr * WM + m * 16 + (lane >> 4) * 4 + j;
                    float v = acc[m][n][j] + bias;
                    if (EPI == 2) v = fmaxf(v, 0.f);
                    if (EPI == 0) C[(long)row * N + col] = v;
                    else          Cb[(long)row * N + col] = f2b(v);
                }
            }
        }
    } else {
        // Fused LSTM cell. Requires BN=128 (FN==4: n indexes gates i,f,g,o).
        const int L = lane & 15;
        const int d = ((col0 >> 6) + wc) * 16 + L;     // 0..511
        float bI = b1[col0 + wc * WN + 0 * 16 + L];
        float bF = b1[col0 + wc * WN + 1 * 16 + L];
        float bG = b1[col0 + wc * WN + 2 * 16 + L];
        float bO = b1[col0 + wc * WN + 3 * 16 + L];
#pragma unroll
        for (int m = 0; m < FM; ++m) {
#pragma unroll
            for (int j = 0; j < 4; ++j) {
                int row = row0 + wr * WM + m * 16 + (lane >> 4) * 4 + j;
                long idx = (long)row * Dd + d;
                float gi = acc[m][0][j] + bI;
                float gf = acc[m][1][j] + bF;
                float gg = acc[m][2][j] + bG;
                float go = acc[m][3][j] + bO;
                float si = 1.f / (1.f + expf(-gi));
                float sf = 1.f / (1.f + expf(-gf));
                float so = 1.f / (1.f + expf(-go));
                float cold = (EPI == 3) ? 0.f : cst[idx];
                float cn = sf * cold + si * tanhf(gg);
                float hn = so * tanhf(cn);
                if (EPI == 5) {
                    float o = addsrc[idx] + hn;
                    lat[idx] = o;
                    latb[idx] = f2b(o);
                } else {
                    cst[idx] = cn;
                    Cb[idx] = f2b(hn);
                }
            }
        }
    }
}

// ---------------------------------------------------------------------------
// MFMA attention. One block per (b, h, q-half): Q 64 rows, K/V 128 rows.
// qkv bf16 [1024][1536]. Writes O bf16 to Ob [1024][512].
__global__ __launch_bounds__(256) void attn_k(const ushort_t* __restrict__ qkv,
                                              ushort_t* __restrict__ Ob) {
    const int blk = blockIdx.x;            // (b*8+h)*2 + qb
    const int qb = blk & 1;
    const int bh = blk >> 1;
    const int h = bh & 7, b = bh >> 3;
    const int tid = threadIdx.x, lane = tid & 63, wid = tid >> 6;
    const int wr = wid >> 1, wc = wid & 1;
    const long qp = 3 * Dd;                // 1536

    __shared__ __align__(16) char smem[32768];
    ushort_t* Qs = (ushort_t*)smem;              // [64][64]  8KB   (phase A)
    ushort_t* Ks = (ushort_t*)(smem + 8192);     // [128][64] 16KB  (phase A)
    float*    Sf = (float*)smem;                 // [64][128] 32KB  (phase B)
    ushort_t* Ps = (ushort_t*)smem;              // [64][128] 16KB  (phase C)
    ushort_t* Vt = (ushort_t*)(smem + 16384);    // [64][128] 16KB  (phase C)

    // ---- load Q (64x64) and K (128x64), CH=8 swizzle ----
#pragma unroll
    for (int i = 0; i < 2; ++i) {
        int j = i * 256 + tid;                  // 0..511
        int r = j >> 3, cl = j & 7, cs = cl ^ (r & 7);
        bf16x8 v = *reinterpret_cast<const bf16x8*>(
            qkv + (long)(b * Ss + qb * 64 + r) * qp + h * DK + cl * 8);
        *reinterpret_cast<bf16x8*>(Qs + r * 64 + cs * 8) = v;
    }
#pragma unroll
    for (int i = 0; i < 4; ++i) {
        int j = i * 256 + tid;                  // 0..1023
        int r = j >> 3, cl = j & 7, cs = cl ^ (r & 7);
        bf16x8 v = *reinterpret_cast<const bf16x8*>(
            qkv + (long)(b * Ss + r) * qp + Dd + h * DK + cl * 8);
        *reinterpret_cast<bf16x8*>(Ks + r * 64 + cs * 8) = v;
    }
    __syncthreads();

    // ---- S = Q K^T : M=64 N=128 K=64; WM=32 WN=64 -> FM=2 FN=4, kk=0..1 ----
    f32x4 acc[2][4];
#pragma unroll
    for (int m = 0; m < 2; ++m)
#pragma unroll
        for (int n = 0; n < 4; ++n) acc[m][n] = (f32x4)(0.0f);
#pragma unroll
    for (int kk = 0; kk < 2; ++kk) {
        bf16x8 af[2], wf[4];
#pragma unroll
        for (int m = 0; m < 2; ++m) {
            int r = wr * 32 + m * 16 + (lane & 15);
            int cl = kk * 4 + (lane >> 4), cs = cl ^ (r & 7);
            af[m] = *reinterpret_cast<const bf16x8*>(Qs + r * 64 + cs * 8);
        }
#pragma unroll
        for (int n = 0; n < 4; ++n) {
            int r = wc * 64 + n * 16 + (lane & 15);
            int cl = kk * 4 + (lane >> 4), cs = cl ^ (r & 7);
            wf[n] = *reinterpret_cast<const bf16x8*>(Ks + r * 64 + cs * 8);
        }
#pragma unroll
        for (int m = 0; m < 2; ++m)
#pragma unroll
            for (int n = 0; n < 4; ++n)
                acc[m][n] = __builtin_amdgcn_mfma_f32_16x16x32_bf16(
                    af[m], wf[n], acc[m][n], 0, 0, 0);
    }
    __syncthreads();   // Q/K dead; reuse smem for S
#pragma unroll
    for (int m = 0; m < 2; ++m)
#pragma unroll
        for (int n = 0; n < 4; ++n)
#pragma unroll
            for (int j = 0; j < 4; ++j) {
                int row = wr * 32 + m * 16 + (lane >> 4) * 4 + j;
                int col = wc * 64 + n * 16 + (lane & 15);
                Sf[row * 128 + col] = acc[m][n][j] * SCALE;
            }
    __syncthreads();

    // ---- softmax: 4 threads per row, 32 cols each (staggered reads) ----
    const int r = tid >> 2, q4 = tid & 3;
    const int qglob = qb * 64 + r;
    const int kbase = q4 * 32;
    float pv[32];
    float mx = -INFINITY;
#pragma unroll
    for (int i4 = 0; i4 < 8; ++i4) {
        int c4 = (i4 + (r & 7)) & 7;
        float4 v = *reinterpret_cast<const float4*>(&Sf[r * 128 + kbase + c4 * 4]);
#pragma unroll
        for (int e = 0; e < 4; ++e) {
            int kcol = kbase + c4 * 4 + e;
            float s = (e == 0) ? v.x : (e == 1) ? v.y : (e == 2) ? v.z : v.w;
            pv[i4 * 4 + e] = s;
            if (kcol <= qglob) mx = fmaxf(mx, s);
        }
    }
    mx = fmaxf(mx, __shfl_xor(mx, 1));
    mx = fmaxf(mx, __shfl_xor(mx, 2));
    float sum = 0.f;
#pragma unroll
    for (int i4 = 0; i4 < 8; ++i4) {
        int c4 = (i4 + (r & 7)) & 7;
#pragma unroll
        for (int e = 0; e < 4; ++e) {
            int kcol = kbase + c4 * 4 + e;
            float p = (kcol <= qglob) ? expf(pv[i4 * 4 + e] - mx) : 0.f;
            pv[i4 * 4 + e] = p;
            sum += p;
        }
    }
    sum += __shfl_xor(sum, 1);
    sum += __shfl_xor(sum, 2);
    float inv = 1.f / sum;
    __syncthreads();   // all S reads complete; smem reusable

    // write P bf16 (CH=16 swizzle), pair stores
#pragma unroll
    for (int i4 = 0; i4 < 8; ++i4) {
        int c4 = (i4 + (r & 7)) & 7;
#pragma unroll
        for (int e2 = 0; e2 < 2; ++e2) {
            int k0 = kbase + c4 * 4 + e2 * 2;
            int cl = k0 >> 3, cs = cl ^ (r & 15);
            ushort2 pr;
            pr.x = f2b(pv[i4 * 4 + e2 * 2] * inv);
            pr.y = f2b(pv[i4 * 4 + e2 * 2 + 1] * inv);
            *reinterpret_cast<ushort2*>(Ps + r * 128 + cs * 8 + (k0 & 7)) = pr;
        }
    }
    // load V -> Vt[d][s] transposed (CH=16 swizzle)
#pragma unroll
    for (int i = 0; i < 4; ++i) {
        int j = i * 256 + tid;                 // chunk: s=j>>3, d-chunk=j&7
        int s = j >> 3, dc = j & 7;
        bf16x8 v = *reinterpret_cast<const bf16x8*>(
            qkv + (long)(b * Ss + s) * qp + 2 * Dd + h * DK + dc * 8);
        int cl = s >> 3;
#pragma unroll
        for (int e = 0; e < 8; ++e) {
            int d = dc * 8 + e;
            int cs = cl ^ (d & 15);
            Vt[d * 128 + cs * 8 + (s & 7)] = ((ushort_t*)&v)[e];
        }
    }
    __syncthreads();

    // ---- O = P V : M=64 N=64 K=128; WM=32 WN=32 -> FM=2 FN=2, kk=0..3 ----
    f32x4 acc2[2][2];
#pragma unroll
    for (int m = 0; m < 2; ++m)
#pragma unroll
        for (int n = 0; n < 2; ++n) acc2[m][n] = (f32x4)(0.0f);
#pragma unroll
    for (int kk = 0; kk < 4; ++kk) {
        bf16x8 af[2], wf[2];
#pragma unroll
        for (int m = 0; m < 2; ++m) {
            int rr = wr * 32 + m * 16 + (lane & 15);
            int cl = kk * 4 + (lane >> 4), cs = cl ^ (rr & 15);
            af[m] = *reinterpret_cast<const bf16x8*>(Ps + rr * 128 + cs * 8);
        }
#pragma unroll
        for (int n = 0; n < 2; ++n) {
            int rd = wc * 32 + n * 16 + (lane & 15);
            int cl = kk * 4 + (lane >> 4), cs = cl ^ (rd & 15);
            wf[n] = *reinterpret_cast<const bf16x8*>(Vt + rd * 128 + cs * 8);
        }
#pragma unroll
        for (int m = 0; m < 2; ++m)
#pragma unroll
            for (int n = 0; n < 2; ++n)
                acc2[m][n] = __builtin_amdgcn_mfma_f32_16x16x32_bf16(
                    af[m], wf[n], acc2[m][n], 0, 0, 0);
    }
#pragma unroll
    for (int m = 0; m < 2; ++m)
#pragma unroll
        for (int n = 0; n < 2; ++n)
#pragma unroll
            for (int j = 0; j < 4; ++j) {
                int q = wr * 32 + m * 16 + (lane >> 4) * 4 + j;
                int d = wc * 32 + n * 16 + (lane & 15);
                Ob[(long)(b * Ss + qb * 64 + q) * Dd + h * DK + d] = f2b(acc2[m][n][j]);
            }
}

// ---------------------------------------------------------------------------
// out = LayerNorm(a + bsrc) * w + bias  -> f32 + bf16
__global__ __launch_bounds__(256) void add_ln_k(float* __restrict__ out,
                                                ushort_t* __restrict__ outb,
                                                const float* __restrict__ a,
                                                const float* __restrict__ bsrc,
                                                const float* __restrict__ w,
                                                const float* __restrict__ bias) {
    const int t = blockIdx.x;
    const int tid = threadIdx.x;
    float2 av = *reinterpret_cast<const float2*>(&a[(long)t * Dd + tid * 2]);
    float2 bv = *reinterpret_cast<const float2*>(&bsrc[(long)t * Dd + tid * 2]);
    float x0 = av.x + bv.x, x1 = av.y + bv.y;
    float s = x0 + x1, ss = x0 * x0 + x1 * x1;
    for (int off = 1; off < 64; off <<= 1) {
        s += __shfl_xor(s, off);
        ss += __shfl_xor(ss, off);
    }
    __shared__ float sm[4], ssm[4];
    int wid = tid >> 6;
    if ((tid & 63) == 0) { sm[wid] = s; ssm[wid] = ss; }
    __syncthreads();
    s = sm[0] + sm[1] + sm[2] + sm[3];
    ss = ssm[0] + ssm[1] + ssm[2] + ssm[3];
    float mean = s * (1.f / Dd);
    float var = ss * (1.f / Dd) - mean * mean;
    float rstd = rsqrtf(var + 1e-5f);
    float o0 = (x0 - mean) * rstd * w[tid * 2] + bias[tid * 2];
    float o1 = (x1 - mean) * rstd * w[tid * 2 + 1] + bias[tid * 2 + 1];
    out[(long)t * Dd + tid * 2]     = o0;
    out[(long)t * Dd + tid * 2 + 1] = o1;
    ushort2 ob; ob.x = f2b(o0); ob.y = f2b(o1);
    *reinterpret_cast<ushort2*>(&outb[(long)t * Dd + tid * 2]) = ob;
}

// ---------------------------------------------------------------------------
extern "C" void kernel_launch(void* const* d_in, const int* in_sizes, int n_in,
                              void* d_out, int out_size, void* d_ws, size_t ws_size,
                              hipStream_t stream) {
    const int*   tokens     = (const int*)  d_in[0];
    const float* emb        = (const float*)d_in[1];
    const float* in_proj_w  = (const float*)d_in[2];
    const float* in_proj_b  = (const float*)d_in[3];
    const float* attn_out_w = (const float*)d_in[4];
    const float* attn_out_b = (const float*)d_in[5];
    const float* ln1_w      = (const float*)d_in[6];
    const float* ln1_b      = (const float*)d_in[7];
    const float* lstm_wih   = (const float*)d_in[8];
    const float* lstm_whh   = (const float*)d_in[9];
    const float* lstm_bih   = (const float*)d_in[10];
    const float* lstm_bhh   = (const float*)d_in[11];
    const float* ff_w1      = (const float*)d_in[12];
    const float* ff_b1      = (const float*)d_in[13];
    const float* ff_w2      = (const float*)d_in[14];
    const float* ff_b2      = (const float*)d_in[15];
    const float* ln2_w      = (const float*)d_in[16];
    const float* ln2_b      = (const float*)d_in[17];
    const float* head_w     = (const float*)d_in[18];
    const float* head_bias  = (const float*)d_in[19];
    float* out = (float*)d_out;

    // ---- workspace layout ----
    const long TD = (long)Tt * Dd;          // 524288
    float* ws    = (float*)d_ws;
    float* X     = ws;                      // residual (f32)
    float* Cst   = X + TD;                  // LSTM cell state
    float* LAT   = Cst + TD;
    float* Ta    = LAT + TD;                // ffn2 out f32
    float* Tb    = Ta + TD;                 // out-proj out f32
    float* biasb = Tb + TD;                 // 4 x 2048 reordered lstm bias
    ushort_t* Xb   = (ushort_t*)(biasb + (long)Ll * 2048);
    ushort_t* H1b  = Xb + TD;
    ushort_t* H2b  = H1b + TD;
    ushort_t* LATb = H2b + TD;
    ushort_t* Tab  = LATb + TD;
    ushort_t* BIGb = Tab + TD;              // 1024 x 2048 (qkv / ffn1)
    ushort_t* ipw   = BIGb + (long)Tt * 2048;
    ushort_t* aow   = ipw + (long)Ll * 3 * Dd * Dd;
    ushort_t* wihb  = aow + (long)Ll * Dd * Dd;     // gate-interleaved
    ushort_t* wsumb = wihb + (long)Ll * 4 * Dd * Dd; // gate-interleaved wih+whh
    ushort_t* ff1b  = wsumb + (long)Ll * 4 * Dd * Dd;
    ushort_t* ff2b  = ff1b + (long)Ll * Pp * Dd;
    ushort_t* hwb   = ff2b + (long)Ll * Dd * Pp;

    // ---- fused weight conversion (8 segments, one kernel) ----
    CvtSegs segs;
    long cum = 0;
    auto set = [&](int k, const float* a, const float* b, void* d, long n4, int mode) {
        segs.a[k] = a; segs.b[k] = b; segs.d[k] = d; segs.mode[k] = mode;
        cum += n4; segs.end4[k] = cum;
    };
    set(0, in_proj_w,  nullptr,  ipw,   (long)Ll * 3 * Dd * Dd / 4, 0);
    set(1, attn_out_w, nullptr,  aow,   (long)Ll * Dd * Dd / 4,     0);
    set(2, lstm_wih,   nullptr,  wihb,  (long)Ll * 4 * Dd * Dd / 4, 2);
    set(3, lstm_wih,   lstm_whh, wsumb, (long)Ll * 4 * Dd * Dd / 4, 3);
    set(4, lstm_bih,   lstm_bhh, biasb, (long)Ll * 2048 / 4,        4);
    set(5, ff_w1,      nullptr,  ff1b,  (long)Ll * Pp * Dd / 4,     0);
    set(6, ff_w2,      nullptr,  ff2b,  (long)Ll * Dd * Pp / 4,     0);
    set(7, head_w,     nullptr,  hwb,   (long)Vv * Dd / 4,          0);
    cvt_all_k<<<(int)(cum / 256), 256, 0, stream>>>(segs);

    embed_k<<<Tt, 128, 0, stream>>>(tokens, emb, X, Xb);

    for (int l = 0; l < Ll; ++l) {
        // --- attention ---
        gemm_bf16<64, 128, 64, 1><<<dim3(3 * Dd / 128, Tt / 64), 256, 0, stream>>>(
            Xb, ipw + (long)l * 3 * Dd * Dd, in_proj_b + (long)l * 3 * Dd,
            nullptr, BIGb, nullptr, nullptr, nullptr, nullptr, Tt, 3 * Dd, Dd);
        attn_k<<<Bb * Hh * 2, 256, 0, stream>>>(BIGb, Tab);
        gemm_bf16<64, 64, 64, 0><<<dim3(Dd / 64, Tt / 64), 256, 0, stream>>>(
            Tab, aow + (long)l * Dd * Dd, attn_out_b + (long)l * Dd,
            Tb, nullptr, nullptr, nullptr, nullptr, nullptr, Tt, Dd, Dd);
        add_ln_k<<<Tt, 256, 0, stream>>>(X, Xb, X, Tb,
                                         ln1_w + (long)l * Dd, ln1_b + (long)l * Dd);

        // --- LSTM latent recurrence (gate-interleaved, cell math fused) ---
        const float* bl = biasb + (long)l * 2048;
        gemm_bf16<64, 128, 64, 3><<<dim3(16, 16), 256, 0, stream>>>(
            Xb, wihb + (long)l * 4 * Dd * Dd, bl,
            nullptr, H1b, Cst, nullptr, nullptr, nullptr, Tt, 4 * Dd, Dd);
        gemm_bf16<64, 128, 64, 4><<<dim3(16, 16), 256, 0, stream>>>(
            H1b, wsumb + (long)l * 4 * Dd * Dd, bl,
            nullptr, H2b, Cst, nullptr, nullptr, nullptr, Tt, 4 * Dd, Dd);
        gemm_bf16<64, 128, 64, 5><<<dim3(16, 16), 256, 0, stream>>>(
            H2b, wsumb + (long)l * 4 * Dd * Dd, bl,
            nullptr, nullptr, Cst, X, LAT, LATb, Tt, 4 * Dd, Dd);

        // --- feed forward ---
        gemm_bf16<64, 128, 64, 2><<<dim3(Pp / 128, Tt / 64), 256, 0, stream>>>(
            LATb, ff1b + (long)l * Pp * Dd, ff_b1 + (long)l * Pp,
            nullptr, BIGb, nullptr, nullptr, nullptr, nullptr, Tt, Pp, Dd);
        gemm_bf16<64, 64, 64, 0><<<dim3(Dd / 64, Tt / 64), 256, 0, stream>>>(
            BIGb, ff2b + (long)l * Dd * Pp, ff_b2 + (long)l * Dd,
            Ta, nullptr, nullptr, nullptr, nullptr, nullptr, Tt, Dd, Pp);
        add_ln_k<<<Tt, 256, 0, stream>>>(X, Xb, LAT, Ta,
                                         ln2_w + (long)l * Dd, ln2_b + (long)l * Dd);
    }

    // --- head: M=1024, N=32768, K=512 ---
    gemm_bf16<128, 128, 32, 0><<<dim3(Vv / 128, Tt / 128), 256, 0, stream>>>(
        Xb, hwb, head_bias,
        out, nullptr, nullptr, nullptr, nullptr, nullptr, Tt, Vv, Dd);
}

// Round 6
// 686.830 us; speedup vs baseline: 1.4252x; 1.0830x over previous
//
#include <hip/hip_runtime.h>
#include <hip/hip_bf16.h>
#include <math.h>

typedef unsigned short ushort_t;
typedef __bf16 bf16x8 __attribute__((ext_vector_type(8)));
typedef float f32x4 __attribute__((ext_vector_type(4)));

// Problem constants
constexpr int Bb = 8, Ss = 128, Dd = 512, Vv = 32768, Hh = 8, Pp = 2048, Ll = 4;
constexpr int Tt = Bb * Ss;          // 1024 tokens
constexpr int DK = Dd / Hh;          // 64
constexpr float SCALE = 0.125f;      // 1/sqrt(64)
constexpr long TDc = (long)Tt * Dd;  // 524288

// fp32 -> bf16 RNE
__device__ __forceinline__ ushort_t f2b(float f) {
    unsigned u = __float_as_uint(f);
    unsigned r = (u + 0x7FFFu + ((u >> 16) & 1u)) >> 16;
    return (ushort_t)r;
}

__device__ __forceinline__ void gload_lds16(const void* g, void* l) {
    __builtin_amdgcn_global_load_lds((const __attribute__((address_space(1))) void*)g,
                                     (__attribute__((address_space(3))) void*)l, 16, 0, 0);
}

// counted vmem wait + barrier with compiler memory fences (T4; rule #18 safe)
template <int N> __device__ __forceinline__ void vwait() {
    asm volatile("s_waitcnt vmcnt(%0)" :: "n"(N) : "memory");
}
__device__ __forceinline__ void barrier_raw() {
    asm volatile("s_barrier" ::: "memory");
}

// ---------------------------------------------------------------------------
// Fused conversion pass. mode: 0=copy,1=a+b,2=perm-LSTM-W copy,3=perm-LSTM-W a+b,
// 4=perm-LSTM-bias a+b (f32 out). Gate interleave: reordered row r' <- src row
// g*512+d with g=(r'>>4)&3, d=(r'>>6)*16+(r'&15)  (matches LSTM GEMM epilogue).
struct CvtSegs {
    const float* a[8];
    const float* b[8];
    void*        d[8];
    long         end4[8];
    int          mode[8];
};

__global__ __launch_bounds__(256) void cvt_all_k(CvtSegs s) {
    long i = (long)blockIdx.x * 256 + threadIdx.x;   // float4 index
    int k = 0;
    while (k < 7 && i >= s.end4[k]) ++k;
    long base = k ? s.end4[k - 1] : 0;
    long j = i - base;
    int mode = s.mode[k];
    long srcj = j;
    if (mode == 2 || mode == 3) {
        const long per = 2048L * 128;          // f4 per layer
        long layer = j / per, rem = j % per;
        long drow = rem >> 7, col4 = rem & 127;
        long g = (drow >> 4) & 3, d = (drow >> 6) * 16 + (drow & 15);
        srcj = layer * per + (g * 512 + d) * 128 + col4;
    } else if (mode == 4) {
        const long per = 512;                  // f4 per layer (2048 elems)
        long layer = j / per, rem = j % per;
        long e0 = rem * 4;
        long g = (e0 >> 4) & 3, d = (e0 >> 6) * 16 + (e0 & 15);
        srcj = layer * per + (g * 512 + d) / 4;
    }
    float4 v = reinterpret_cast<const float4*>(s.a[k])[srcj];
    if (s.b[k]) {
        float4 vb = reinterpret_cast<const float4*>(s.b[k])[srcj];
        v.x += vb.x; v.y += vb.y; v.z += vb.z; v.w += vb.w;
    }
    if (mode == 4) {
        reinterpret_cast<float4*>(s.d[k])[j] = v;
    } else {
        ushort4 o;
        o.x = f2b(v.x); o.y = f2b(v.y); o.z = f2b(v.z); o.w = f2b(v.w);
        reinterpret_cast<ushort4*>(s.d[k])[j] = o;
    }
}

// ---------------------------------------------------------------------------
__global__ __launch_bounds__(128) void embed_k(const int* __restrict__ tokens,
                                               const float* __restrict__ emb,
                                               float* __restrict__ X,
                                               ushort_t* __restrict__ Xb) {
    int t = blockIdx.x;
    int tok = tokens[t];
    float4 v = reinterpret_cast<const float4*>(emb + (long)tok * Dd)[threadIdx.x];
    reinterpret_cast<float4*>(X + (long)t * Dd)[threadIdx.x] = v;
    ushort4 o;
    o.x = f2b(v.x); o.y = f2b(v.y); o.z = f2b(v.z); o.w = f2b(v.w);
    reinterpret_cast<ushort4*>(Xb + (long)t * Dd)[threadIdx.x] = o;
}

// ---------------------------------------------------------------------------
// bf16 MFMA GEMM, 3-buffer 2-deep pipeline with counted vmcnt (T3/T4-min):
//   prologue: STAGE(0),STAGE(1)
//   iter t:   vwait(tile t done, newest stage in flight); s_barrier;
//             STAGE(t+2); ds_read+MFMA on buf t%3.     (never vmcnt(0) mid-loop)
// EPI: 0 = f32 out (+bias, split-K partials); 1 = bf16 out; 2 = ReLU bf16;
//      3/4/5 = fused LSTM cell (first/mid/last) on gate-interleaved layout.
template <int BM, int BN, int BK, int EPI, int SPLITS>
__global__ __launch_bounds__(256) void gemm_bf16(const ushort_t* __restrict__ A,
                                                 const ushort_t* __restrict__ W,
                                                 const float* __restrict__ b1,
                                                 float* __restrict__ C,
                                                 ushort_t* __restrict__ Cb,
                                                 float* __restrict__ cst,
                                                 const float* __restrict__ addsrc,
                                                 float* __restrict__ lat,
                                                 ushort_t* __restrict__ latb,
                                                 int M, int N, int K) {
    constexpr int CH = BK / 8;                 // 16B chunks per row
    constexpr int SH = (CH == 4) ? 1 : 0;      // swizzle shift
    constexpr int WM = BM / 2, WN = BN / 2;
    constexpr int FM = WM / 16, FN = WN / 16;
    constexpr int LA = BM * BK / 2048;
    constexpr int LW = BN * BK / 2048;
    constexpr int LPB = LA + LW;               // vmem insts per thread per stage

    __shared__ __align__(16) ushort_t As[3][BM * BK];
    __shared__ __align__(16) ushort_t Ws[3][BN * BK];

    const int tid = threadIdx.x;
    const int lane = tid & 63, wid = tid >> 6;
    const int wr = wid >> 1, wc = wid & 1;
    const int row0 = blockIdx.y * BM, col0 = blockIdx.x * BN;
    const int z = (SPLITS > 1) ? blockIdx.z : 0;
    const int KS = K / SPLITS;
    const int kbase = z * KS;
    const int NT = KS / BK;

    auto stage = [&](int buf, int k0) {
#pragma unroll
        for (int i = 0; i < LA; ++i) {
            int j = i * 256 + tid;
            int prow = j / CH;
            int pkg = j & (CH - 1);
            int skg = pkg ^ ((prow >> SH) & (CH - 1));
            gload_lds16(A + (long)(row0 + prow) * K + k0 + skg * 8,
                        &As[buf][(i * 256 + wid * 64) * 8]);
        }
#pragma unroll
        for (int i = 0; i < LW; ++i) {
            int j = i * 256 + tid;
            int prow = j / CH;
            int pkg = j & (CH - 1);
            int skg = pkg ^ ((prow >> SH) & (CH - 1));
            gload_lds16(W + (long)(col0 + prow) * K + k0 + skg * 8,
                        &Ws[buf][(i * 256 + wid * 64) * 8]);
        }
    };

    f32x4 acc[FM][FN];
#pragma unroll
    for (int m = 0; m < FM; ++m)
#pragma unroll
        for (int n = 0; n < FN; ++n) acc[m][n] = (f32x4)(0.0f);

    stage(0, kbase);
    if (NT > 1) stage(1, kbase + BK);

    for (int t = 0; t < NT; ++t) {
        // tile t loads (mine) complete; newest stage may stay in flight
        if (t + 1 < NT) vwait<LPB>(); else vwait<0>();
        barrier_raw();                       // all threads' tile-t data in LDS
        if (t + 2 < NT) stage((t + 2) % 3, kbase + (t + 2) * BK);
        const ushort_t* Ab = As[t % 3];
        const ushort_t* Wb = Ws[t % 3];
#pragma unroll
        for (int kk = 0; kk < BK / 32; ++kk) {
            bf16x8 af[FM], wf[FN];
#pragma unroll
            for (int m = 0; m < FM; ++m) {
                int r = wr * WM + m * 16 + (lane & 15);
                int cl = kk * 4 + (lane >> 4);
                int cs = cl ^ ((r >> SH) & (CH - 1));
                af[m] = *reinterpret_cast<const bf16x8*>(&Ab[r * BK + cs * 8]);
            }
#pragma unroll
            for (int n = 0; n < FN; ++n) {
                int r = wc * WN + n * 16 + (lane & 15);
                int cl = kk * 4 + (lane >> 4);
                int cs = cl ^ ((r >> SH) & (CH - 1));
                wf[n] = *reinterpret_cast<const bf16x8*>(&Wb[r * BK + cs * 8]);
            }
#pragma unroll
            for (int m = 0; m < FM; ++m)
#pragma unroll
                for (int n = 0; n < FN; ++n)
                    acc[m][n] = __builtin_amdgcn_mfma_f32_16x16x32_bf16(
                        af[m], wf[n], acc[m][n], 0, 0, 0);
        }
        // next iter's barrier protects buf reuse (compute t done block-wide there)
    }

    if constexpr (EPI <= 2) {
        float* Cz = C + (long)z * M * N;     // split-K partial plane
#pragma unroll
        for (int n = 0; n < FN; ++n) {
            int col = col0 + wc * WN + n * 16 + (lane & 15);
            float bias = (z == 0) ? b1[col] : 0.f;
#pragma unroll
            for (int m = 0; m < FM; ++m) {
#pragma unroll
                for (int j = 0; j < 4; ++j) {
                    int row = row0 + wr * WM + m * 16 + (lane >> 4) * 4 + j;
                    float v = acc[m][n][j] + bias;
                    if (EPI == 2) v = fmaxf(v, 0.f);
                    if (EPI == 0) Cz[(long)row * N + col] = v;
                    else          Cb[(long)row * N + col] = f2b(v);
                }
            }
        }
    } else {
        // Fused LSTM cell. Requires BN=128 (FN==4: n indexes gates i,f,g,o).
        const int L = lane & 15;
        const int d = ((col0 >> 6) + wc) * 16 + L;     // 0..511
        float bI = b1[col0 + wc * WN + 0 * 16 + L];
        float bF = b1[col0 + wc * WN + 1 * 16 + L];
        float bG = b1[col0 + wc * WN + 2 * 16 + L];
        float bO = b1[col0 + wc * WN + 3 * 16 + L];
#pragma unroll
        for (int m = 0; m < FM; ++m) {
#pragma unroll
            for (int j = 0; j < 4; ++j) {
                int row = row0 + wr * WM + m * 16 + (lane >> 4) * 4 + j;
                long idx = (long)row * Dd + d;
                float gi = acc[m][0][j] + bI;
                float gf = acc[m][1][j] + bF;
                float gg = acc[m][2][j] + bG;
                float go = acc[m][3][j] + bO;
                float si = 1.f / (1.f + expf(-gi));
                float sf = 1.f / (1.f + expf(-gf));
                float so = 1.f / (1.f + expf(-go));
                float cold = (EPI == 3) ? 0.f : cst[idx];
                float cn = sf * cold + si * tanhf(gg);
                float hn = so * tanhf(cn);
                if (EPI == 5) {
                    float o = addsrc[idx] + hn;
                    lat[idx] = o;
                    latb[idx] = f2b(o);
                } else {
                    cst[idx] = cn;
                    Cb[idx] = f2b(hn);
                }
            }
        }
    }
}

// ---------------------------------------------------------------------------
// MFMA attention. One block per (b, h, q-half): Q 64 rows, K/V 128 rows.
// qkv bf16 [1024][1536]. Writes O bf16 to Ob [1024][512].
__global__ __launch_bounds__(256) void attn_k(const ushort_t* __restrict__ qkv,
                                              ushort_t* __restrict__ Ob) {
    const int blk = blockIdx.x;            // (b*8+h)*2 + qb
    const int qb = blk & 1;
    const int bh = blk >> 1;
    const int h = bh & 7, b = bh >> 3;
    const int tid = threadIdx.x, lane = tid & 63, wid = tid >> 6;
    const int wr = wid >> 1, wc = wid & 1;
    const long qp = 3 * Dd;                // 1536

    __shared__ __align__(16) char smem[32768];
    ushort_t* Qs = (ushort_t*)smem;              // [64][64]  8KB   (phase A)
    ushort_t* Ks = (ushort_t*)(smem + 8192);     // [128][64] 16KB  (phase A)
    float*    Sf = (float*)smem;                 // [64][128] 32KB  (phase B)
    ushort_t* Ps = (ushort_t*)smem;              // [64][128] 16KB  (phase C)
    ushort_t* Vt = (ushort_t*)(smem + 16384);    // [64][128] 16KB  (phase C)

    // ---- load Q (64x64) and K (128x64), CH=8 swizzle ----
#pragma unroll
    for (int i = 0; i < 2; ++i) {
        int j = i * 256 + tid;                  // 0..511
        int r = j >> 3, cl = j & 7, cs = cl ^ (r & 7);
        bf16x8 v = *reinterpret_cast<const bf16x8*>(
            qkv + (long)(b * Ss + qb * 64 + r) * qp + h * DK + cl * 8);
        *reinterpret_cast<bf16x8*>(Qs + r * 64 + cs * 8) = v;
    }
#pragma unroll
    for (int i = 0; i < 4; ++i) {
        int j = i * 256 + tid;                  // 0..1023
        int r = j >> 3, cl = j & 7, cs = cl ^ (r & 7);
        bf16x8 v = *reinterpret_cast<const bf16x8*>(
            qkv + (long)(b * Ss + r) * qp + Dd + h * DK + cl * 8);
        *reinterpret_cast<bf16x8*>(Ks + r * 64 + cs * 8) = v;
    }
    __syncthreads();

    // ---- S = Q K^T : M=64 N=128 K=64; WM=32 WN=64 -> FM=2 FN=4, kk=0..1 ----
    f32x4 acc[2][4];
#pragma unroll
    for (int m = 0; m < 2; ++m)
#pragma unroll
        for (int n = 0; n < 4; ++n) acc[m][n] = (f32x4)(0.0f);
#pragma unroll
    for (int kk = 0; kk < 2; ++kk) {
        bf16x8 af[2], wf[4];
#pragma unroll
        for (int m = 0; m < 2; ++m) {
            int r = wr * 32 + m * 16 + (lane & 15);
            int cl = kk * 4 + (lane >> 4), cs = cl ^ (r & 7);
            af[m] = *reinterpret_cast<const bf16x8*>(Qs + r * 64 + cs * 8);
        }
#pragma unroll
        for (int n = 0; n < 4; ++n) {
            int r = wc * 64 + n * 16 + (lane & 15);
            int cl = kk * 4 + (lane >> 4), cs = cl ^ (r & 7);
            wf[n] = *reinterpret_cast<const bf16x8*>(Ks + r * 64 + cs * 8);
        }
#pragma unroll
        for (int m = 0; m < 2; ++m)
#pragma unroll
            for (int n = 0; n < 4; ++n)
                acc[m][n] = __builtin_amdgcn_mfma_f32_16x16x32_bf16(
                    af[m], wf[n], acc[m][n], 0, 0, 0);
    }
    __syncthreads();   // Q/K dead; reuse smem for S
#pragma unroll
    for (int m = 0; m < 2; ++m)
#pragma unroll
        for (int n = 0; n < 4; ++n)
#pragma unroll
            for (int j = 0; j < 4; ++j) {
                int row = wr * 32 + m * 16 + (lane >> 4) * 4 + j;
                int col = wc * 64 + n * 16 + (lane & 15);
                Sf[row * 128 + col] = acc[m][n][j] * SCALE;
            }
    __syncthreads();

    // ---- softmax: 4 threads per row, 32 cols each (staggered reads) ----
    const int r = tid >> 2, q4 = tid & 3;
    const int qglob = qb * 64 + r;
    const int kbase = q4 * 32;
    float pv[32];
    float mx = -INFINITY;
#pragma unroll
    for (int i4 = 0; i4 < 8; ++i4) {
        int c4 = (i4 + (r & 7)) & 7;
        float4 v = *reinterpret_cast<const float4*>(&Sf[r * 128 + kbase + c4 * 4]);
#pragma unroll
        for (int e = 0; e < 4; ++e) {
            int kcol = kbase + c4 * 4 + e;
            float s = (e == 0) ? v.x : (e == 1) ? v.y : (e == 2) ? v.z : v.w;
            pv[i4 * 4 + e] = s;
            if (kcol <= qglob) mx = fmaxf(mx, s);
        }
    }
    mx = fmaxf(mx, __shfl_xor(mx, 1));
    mx = fmaxf(mx, __shfl_xor(mx, 2));
    float sum = 0.f;
#pragma unroll
    for (int i4 = 0; i4 < 8; ++i4) {
        int c4 = (i4 + (r & 7)) & 7;
#pragma unroll
        for (int e = 0; e < 4; ++e) {
            int kcol = kbase + c4 * 4 + e;
            float p = (kcol <= qglob) ? expf(pv[i4 * 4 + e] - mx) : 0.f;
            pv[i4 * 4 + e] = p;
            sum += p;
        }
    }
    sum += __shfl_xor(sum, 1);
    sum += __shfl_xor(sum, 2);
    float inv = 1.f / sum;
    __syncthreads();   // all S reads complete; smem reusable

    // write P bf16 (CH=16 swizzle), pair stores
#pragma unroll
    for (int i4 = 0; i4 < 8; ++i4) {
        int c4 = (i4 + (r & 7)) & 7;
#pragma unroll
        for (int e2 = 0; e2 < 2; ++e2) {
            int k0 = kbase + c4 * 4 + e2 * 2;
            int cl = k0 >> 3, cs = cl ^ (r & 15);
            ushort2 pr;
            pr.x = f2b(pv[i4 * 4 + e2 * 2] * inv);
            pr.y = f2b(pv[i4 * 4 + e2 * 2 + 1] * inv);
            *reinterpret_cast<ushort2*>(Ps + r * 128 + cs * 8 + (k0 & 7)) = pr;
        }
    }
    // load V -> Vt[d][s] transposed (CH=16 swizzle)
#pragma unroll
    for (int i = 0; i < 4; ++i) {
        int j = i * 256 + tid;                 // chunk: s=j>>3, d-chunk=j&7
        int s = j >> 3, dc = j & 7;
        bf16x8 v = *reinterpret_cast<const bf16x8*>(
            qkv + (long)(b * Ss + s) * qp + 2 * Dd + h * DK + dc * 8);
        int cl = s >> 3;
#pragma unroll
        for (int e = 0; e < 8; ++e) {
            int d = dc * 8 + e;
            int cs = cl ^ (d & 15);
            Vt[d * 128 + cs * 8 + (s & 7)] = ((ushort_t*)&v)[e];
        }
    }
    __syncthreads();

    // ---- O = P V : M=64 N=64 K=128; WM=32 WN=32 -> FM=2 FN=2, kk=0..3 ----
    f32x4 acc2[2][2];
#pragma unroll
    for (int m = 0; m < 2; ++m)
#pragma unroll
        for (int n = 0; n < 2; ++n) acc2[m][n] = (f32x4)(0.0f);
#pragma unroll
    for (int kk = 0; kk < 4; ++kk) {
        bf16x8 af[2], wf[2];
#pragma unroll
        for (int m = 0; m < 2; ++m) {
            int rr = wr * 32 + m * 16 + (lane & 15);
            int cl = kk * 4 + (lane >> 4), cs = cl ^ (rr & 15);
            af[m] = *reinterpret_cast<const bf16x8*>(Ps + rr * 128 + cs * 8);
        }
#pragma unroll
        for (int n = 0; n < 2; ++n) {
            int rd = wc * 32 + n * 16 + (lane & 15);
            int cl = kk * 4 + (lane >> 4), cs = cl ^ (rd & 15);
            wf[n] = *reinterpret_cast<const bf16x8*>(Vt + rd * 128 + cs * 8);
        }
#pragma unroll
        for (int m = 0; m < 2; ++m)
#pragma unroll
            for (int n = 0; n < 2; ++n)
                acc2[m][n] = __builtin_amdgcn_mfma_f32_16x16x32_bf16(
                    af[m], wf[n], acc2[m][n], 0, 0, 0);
    }
#pragma unroll
    for (int m = 0; m < 2; ++m)
#pragma unroll
        for (int n = 0; n < 2; ++n)
#pragma unroll
            for (int j = 0; j < 4; ++j) {
                int q = wr * 32 + m * 16 + (lane >> 4) * 4 + j;
                int d = wc * 32 + n * 16 + (lane & 15);
                Ob[(long)(b * Ss + qb * 64 + q) * Dd + h * DK + d] = f2b(acc2[m][n][j]);
            }
}

// ---------------------------------------------------------------------------
// out = LayerNorm(a + sum_{p<nparts} parts[p*TD]) * w + bias  -> f32 + bf16
__global__ __launch_bounds__(256) void add_ln_k(float* __restrict__ out,
                                                ushort_t* __restrict__ outb,
                                                const float* __restrict__ a,
                                                const float* __restrict__ parts,
                                                int nparts,
                                                const float* __restrict__ w,
                                                const float* __restrict__ bias) {
    const int t = blockIdx.x;
    const int tid = threadIdx.x;
    float2 av = *reinterpret_cast<const float2*>(&a[(long)t * Dd + tid * 2]);
    float x0 = av.x, x1 = av.y;
    for (int p = 0; p < nparts; ++p) {
        float2 bv = *reinterpret_cast<const float2*>(
            &parts[p * TDc + (long)t * Dd + tid * 2]);
        x0 += bv.x; x1 += bv.y;
    }
    float s = x0 + x1, ss = x0 * x0 + x1 * x1;
    for (int off = 1; off < 64; off <<= 1) {
        s += __shfl_xor(s, off);
        ss += __shfl_xor(ss, off);
    }
    __shared__ float sm[4], ssm[4];
    int wid = tid >> 6;
    if ((tid & 63) == 0) { sm[wid] = s; ssm[wid] = ss; }
    __syncthreads();
    s = sm[0] + sm[1] + sm[2] + sm[3];
    ss = ssm[0] + ssm[1] + ssm[2] + ssm[3];
    float mean = s * (1.f / Dd);
    float var = ss * (1.f / Dd) - mean * mean;
    float rstd = rsqrtf(var + 1e-5f);
    float o0 = (x0 - mean) * rstd * w[tid * 2] + bias[tid * 2];
    float o1 = (x1 - mean) * rstd * w[tid * 2 + 1] + bias[tid * 2 + 1];
    out[(long)t * Dd + tid * 2]     = o0;
    out[(long)t * Dd + tid * 2 + 1] = o1;
    ushort2 ob; ob.x = f2b(o0); ob.y = f2b(o1);
    *reinterpret_cast<ushort2*>(&outb[(long)t * Dd + tid * 2]) = ob;
}

// ---------------------------------------------------------------------------
extern "C" void kernel_launch(void* const* d_in, const int* in_sizes, int n_in,
                              void* d_out, int out_size, void* d_ws, size_t ws_size,
                              hipStream_t stream) {
    const int*   tokens     = (const int*)  d_in[0];
    const float* emb        = (const float*)d_in[1];
    const float* in_proj_w  = (const float*)d_in[2];
    const float* in_proj_b  = (const float*)d_in[3];
    const float* attn_out_w = (const float*)d_in[4];
    const float* attn_out_b = (const float*)d_in[5];
    const float* ln1_w      = (const float*)d_in[6];
    const float* ln1_b      = (const float*)d_in[7];
    const float* lstm_wih   = (const float*)d_in[8];
    const float* lstm_whh   = (const float*)d_in[9];
    const float* lstm_bih   = (const float*)d_in[10];
    const float* lstm_bhh   = (const float*)d_in[11];
    const float* ff_w1      = (const float*)d_in[12];
    const float* ff_b1      = (const float*)d_in[13];
    const float* ff_w2      = (const float*)d_in[14];
    const float* ff_b2      = (const float*)d_in[15];
    const float* ln2_w      = (const float*)d_in[16];
    const float* ln2_b      = (const float*)d_in[17];
    const float* head_w     = (const float*)d_in[18];
    const float* head_bias  = (const float*)d_in[19];
    float* out = (float*)d_out;

    // ---- workspace layout ----
    const long TD = TDc;
    float* ws    = (float*)d_ws;
    float* X     = ws;                      // residual (f32)
    float* Cst   = X + TD;                  // LSTM cell state
    float* LAT   = Cst + TD;
    float* Ta    = LAT + TD;                // ffn2 split-K partials (4 planes)
    float* Tb    = Ta + 4 * TD;             // out-proj split-K partials (2 planes)
    float* biasb = Tb + 2 * TD;             // 4 x 2048 reordered lstm bias
    ushort_t* Xb   = (ushort_t*)(biasb + (long)Ll * 2048);
    ushort_t* H1b  = Xb + TD;
    ushort_t* H2b  = H1b + TD;
    ushort_t* LATb = H2b + TD;
    ushort_t* Tab  = LATb + TD;
    ushort_t* BIGb = Tab + TD;              // 1024 x 2048 (qkv / ffn1)
    ushort_t* ipw   = BIGb + (long)Tt * 2048;
    ushort_t* aow   = ipw + (long)Ll * 3 * Dd * Dd;
    ushort_t* wihb  = aow + (long)Ll * Dd * Dd;      // gate-interleaved
    ushort_t* wsumb = wihb + (long)Ll * 4 * Dd * Dd; // gate-interleaved wih+whh
    ushort_t* ff1b  = wsumb + (long)Ll * 4 * Dd * Dd;
    ushort_t* ff2b  = ff1b + (long)Ll * Pp * Dd;
    ushort_t* hwb   = ff2b + (long)Ll * Dd * Pp;

    // ---- fused weight conversion (8 segments, one kernel) ----
    CvtSegs segs;
    long cum = 0;
    auto set = [&](int k, const float* a, const float* b, void* d, long n4, int mode) {
        segs.a[k] = a; segs.b[k] = b; segs.d[k] = d; segs.mode[k] = mode;
        cum += n4; segs.end4[k] = cum;
    };
    set(0, in_proj_w,  nullptr,  ipw,   (long)Ll * 3 * Dd * Dd / 4, 0);
    set(1, attn_out_w, nullptr,  aow,   (long)Ll * Dd * Dd / 4,     0);
    set(2, lstm_wih,   nullptr,  wihb,  (long)Ll * 4 * Dd * Dd / 4, 2);
    set(3, lstm_wih,   lstm_whh, wsumb, (long)Ll * 4 * Dd * Dd / 4, 3);
    set(4, lstm_bih,   lstm_bhh, biasb, (long)Ll * 2048 / 4,        4);
    set(5, ff_w1,      nullptr,  ff1b,  (long)Ll * Pp * Dd / 4,     0);
    set(6, ff_w2,      nullptr,  ff2b,  (long)Ll * Dd * Pp / 4,     0);
    set(7, head_w,     nullptr,  hwb,   (long)Vv * Dd / 4,          0);
    cvt_all_k<<<(int)(cum / 256), 256, 0, stream>>>(segs);

    embed_k<<<Tt, 128, 0, stream>>>(tokens, emb, X, Xb);

    for (int l = 0; l < Ll; ++l) {
        // --- attention ---
        gemm_bf16<64, 128, 64, 1, 1><<<dim3(3 * Dd / 128, Tt / 64), 256, 0, stream>>>(
            Xb, ipw + (long)l * 3 * Dd * Dd, in_proj_b + (long)l * 3 * Dd,
            nullptr, BIGb, nullptr, nullptr, nullptr, nullptr, Tt, 3 * Dd, Dd);
        attn_k<<<Bb * Hh * 2, 256, 0, stream>>>(BIGb, Tab);
        // out-proj: split-K x2 -> partials Tb[0..1]
        gemm_bf16<64, 64, 64, 0, 2><<<dim3(Dd / 64, Tt / 64, 2), 256, 0, stream>>>(
            Tab, aow + (long)l * Dd * Dd, attn_out_b + (long)l * Dd,
            Tb, nullptr, nullptr, nullptr, nullptr, nullptr, Tt, Dd, Dd);
        add_ln_k<<<Tt, 256, 0, stream>>>(X, Xb, X, Tb, 2,
                                         ln1_w + (long)l * Dd, ln1_b + (long)l * Dd);

        // --- LSTM latent recurrence (gate-interleaved, cell math fused) ---
        const float* bl = biasb + (long)l * 2048;
        gemm_bf16<64, 128, 64, 3, 1><<<dim3(16, 16), 256, 0, stream>>>(
            Xb, wihb + (long)l * 4 * Dd * Dd, bl,
            nullptr, H1b, Cst, nullptr, nullptr, nullptr, Tt, 4 * Dd, Dd);
        gemm_bf16<64, 128, 64, 4, 1><<<dim3(16, 16), 256, 0, stream>>>(
            H1b, wsumb + (long)l * 4 * Dd * Dd, bl,
            nullptr, H2b, Cst, nullptr, nullptr, nullptr, Tt, 4 * Dd, Dd);
        gemm_bf16<64, 128, 64, 5, 1><<<dim3(16, 16), 256, 0, stream>>>(
            H2b, wsumb + (long)l * 4 * Dd * Dd, bl,
            nullptr, nullptr, Cst, X, LAT, LATb, Tt, 4 * Dd, Dd);

        // --- feed forward ---
        gemm_bf16<64, 128, 64, 2, 1><<<dim3(Pp / 128, Tt / 64), 256, 0, stream>>>(
            LATb, ff1b + (long)l * Pp * Dd, ff_b1 + (long)l * Pp,
            nullptr, BIGb, nullptr, nullptr, nullptr, nullptr, Tt, Pp, Dd);
        // ffn2: split-K x4 -> partials Ta[0..3]
        gemm_bf16<64, 64, 64, 0, 4><<<dim3(Dd / 64, Tt / 64, 4), 256, 0, stream>>>(
            BIGb, ff2b + (long)l * Dd * Pp, ff_b2 + (long)l * Dd,
            Ta, nullptr, nullptr, nullptr, nullptr, nullptr, Tt, Dd, Pp);
        add_ln_k<<<Tt, 256, 0, stream>>>(X, Xb, LAT, Ta, 4,
                                         ln2_w + (long)l * Dd, ln2_b + (long)l * Dd);
    }

    // --- head: M=1024, N=32768, K=512 ---
    gemm_bf16<128, 128, 32, 0, 1><<<dim3(Vv / 128, Tt / 128), 256, 0, stream>>>(
        Xb, hwb, head_bias,
        out, nullptr, nullptr, nullptr, nullptr, nullptr, Tt, Vv, Dd);
}